// Round 1
// baseline (590.198 us; speedup 1.0000x reference)
//
#include <hip/hip_runtime.h>
#include <hip/hip_bf16.h>
#include <cstdint>
#include <cstddef>

// Problem dims
#define M_ROWS   4096     // B*T
#define N_VOCAB  32000    // V
#define K_DIM    512      // D
#define S_DIM    400
#define CV_DIM   600
#define T_DIM    128
#define OUT_PITCH 32600   // V + CV
#define PAD_IDX  1

typedef __attribute__((ext_vector_type(8))) short short8;
typedef __attribute__((ext_vector_type(4))) float f32x4;

__device__ inline void gload_lds16(const void* g, void* l) {
  __builtin_amdgcn_global_load_lds(
      (const __attribute__((address_space(1))) unsigned int*)g,
      (__attribute__((address_space(3))) unsigned int*)l, 16, 0, 0);
}

__device__ inline unsigned short f32_to_bf16_rn(float f) {
  unsigned u = __float_as_uint(f);
  u += 0x7FFFu + ((u >> 16) & 1u);
  return (unsigned short)(u >> 16);
}

// ---------- K1a: fp32 -> bf16 conversion (vectorized) ----------
__global__ void cvt_kernel(const float4* __restrict__ in, ushort4* __restrict__ out, unsigned n4) {
  unsigned stride = gridDim.x * blockDim.x;
  for (unsigned i = blockIdx.x * blockDim.x + threadIdx.x; i < n4; i += stride) {
    float4 v = in[i];
    ushort4 o;
    o.x = f32_to_bf16_rn(v.x);
    o.y = f32_to_bf16_rn(v.y);
    o.z = f32_to_bf16_rn(v.z);
    o.w = f32_to_bf16_rn(v.w);
    out[i] = o;
  }
}

// ---------- K1b: copy gate = sigmoid(hidden @ w_copy + b_copy), one wave/row ----------
__global__ void copygate_kernel(const float* __restrict__ hidden, const float* __restrict__ w_copy,
                                const float* __restrict__ b_copy, float* __restrict__ copyg) {
  unsigned gw = (blockIdx.x * blockDim.x + threadIdx.x) >> 6;   // row
  unsigned lane = threadIdx.x & 63u;
  if (gw >= M_ROWS) return;
  const float4* h4 = (const float4*)(hidden + (size_t)gw * K_DIM);
  const float4* w4 = (const float4*)w_copy;
  float dot = 0.f;
  #pragma unroll
  for (int i = 0; i < 2; ++i) {
    float4 a = h4[lane * 2 + i], w = w4[lane * 2 + i];
    dot += a.x * w.x + a.y * w.y + a.z * w.z + a.w * w.w;
  }
  #pragma unroll
  for (int mask = 1; mask < 64; mask <<= 1) dot += __shfl_xor(dot, mask);
  if (lane == 0) copyg[gw] = 1.f / (1.f + __expf(-(dot + b_copy[0])));
}

// ---------- K1c: recover src_ids from one-hot src_map, one wave/(b,s) ----------
__global__ void srcids_kernel(const float* __restrict__ src_map, int* __restrict__ src_ids) {
  unsigned pos = (blockIdx.x * blockDim.x + threadIdx.x) >> 6;  // b*S + s, 12800 total
  unsigned lane = threadIdx.x & 63u;
  if (pos >= 32 * S_DIM) return;
  const float* row = src_map + (size_t)pos * CV_DIM;
  int found = 1 << 30;
  for (int v = lane; v < CV_DIM; v += 64)
    if (row[v] > 0.5f) found = v;
  #pragma unroll
  for (int mask = 1; mask < 64; mask <<= 1) {
    int o = __shfl_xor(found, mask);
    found = found < o ? found : o;
  }
  if (lane == 0) src_ids[pos] = found;
}

// ---------- K2: bf16 MFMA GEMM (C = A * B^T) + exp epilogue + row-sum atomics ----------
// A: hidden bf16 [4096][512], B: W bf16 [32000][512]. 128x128 tile, BK=64,
// 4 waves (2x2), each wave 64x64 via 4x4 fragments of 16x16x32.
__global__ void gemm_exp_kernel(const unsigned short* __restrict__ A,
                                const unsigned short* __restrict__ B,
                                const float* __restrict__ bias,
                                float* __restrict__ out,
                                float* __restrict__ row_sum) {
  __shared__ unsigned short As[128 * 64];
  __shared__ unsigned short Bs[128 * 64];
  unsigned bid = blockIdx.x;
  // bijective XCD swizzle: 8000 blocks, 8000 % 8 == 0
  unsigned wg = (bid & 7u) * 1000u + (bid >> 3);
  unsigned mt = wg / 250u, nt = wg % 250u;
  unsigned m0 = mt * 128u, n0 = nt * 128u;
  unsigned tid = threadIdx.x;
  unsigned lane = tid & 63u;
  unsigned wid = tid >> 6;
  unsigned wm = wid >> 1, wn = wid & 1u;
  unsigned lr = lane >> 4, lc = lane & 15u;

  f32x4 acc[4][4] = {};

  for (unsigned kt = 0; kt < 8; ++kt) {
    unsigned k0 = kt * 64u;
    #pragma unroll
    for (unsigned i = 0; i < 4; ++i) {
      unsigned off = i * 4096u + tid * 16u;    // byte offset into 16KB tile
      unsigned row = off >> 7;                 // 128 B per row
      unsigned col = (off & 127u) >> 1;        // bf16 col
      gload_lds16(A + (size_t)(m0 + row) * K_DIM + k0 + col, (char*)As + off);
      gload_lds16(B + (size_t)(n0 + row) * K_DIM + k0 + col, (char*)Bs + off);
    }
    __syncthreads();   // compiler emits vmcnt(0) drain before barrier
    #pragma unroll
    for (unsigned ks = 0; ks < 2; ++ks) {
      short8 af[4], bf[4];
      #pragma unroll
      for (int m = 0; m < 4; ++m)
        af[m] = *(const short8*)&As[(wm * 64u + m * 16u + lc) * 64u + ks * 32u + lr * 8u];
      #pragma unroll
      for (int n = 0; n < 4; ++n)
        bf[n] = *(const short8*)&Bs[(wn * 64u + n * 16u + lc) * 64u + ks * 32u + lr * 8u];
      #pragma unroll
      for (int m = 0; m < 4; ++m)
        #pragma unroll
        for (int n = 0; n < 4; ++n)
          acc[m][n] = __builtin_amdgcn_mfma_f32_16x16x32_bf16(af[m], bf[n], acc[m][n], 0, 0, 0);
    }
    __syncthreads();
  }

  // epilogue: e = exp(logit + bias) (no max-subtraction needed; |logit| <~ 4),
  // write unnormalized exp, accumulate per-row sums.
  float bv[4];
  #pragma unroll
  for (int n = 0; n < 4; ++n) bv[n] = bias[n0 + wn * 64u + n * 16u + lc];

  #pragma unroll
  for (int m = 0; m < 4; ++m) {
    unsigned grow_base = m0 + wm * 64u + m * 16u + lr * 4u;
    #pragma unroll
    for (int j = 0; j < 4; ++j) {
      unsigned grow = grow_base + j;
      float rs = 0.f;
      #pragma unroll
      for (int n = 0; n < 4; ++n) {
        unsigned gcol = n0 + wn * 64u + n * 16u + lc;
        float e = (gcol == PAD_IDX) ? 0.f : __expf(acc[m][n][j] + bv[n]);
        out[(size_t)grow * OUT_PITCH + gcol] = e;
        rs += e;
      }
      #pragma unroll
      for (int mask = 1; mask < 16; mask <<= 1) rs += __shfl_xor(rs, mask);
      if (lc == 0) atomicAdd(&row_sum[grow], rs);
    }
  }
}

// ---------- K2b: s[r] = (1 - copy[r]) / row_sum[r] ----------
__global__ void finalize_kernel(const float* __restrict__ row_sum, const float* __restrict__ copyg,
                                float* __restrict__ sscale) {
  unsigned r = blockIdx.x * blockDim.x + threadIdx.x;
  if (r < M_ROWS) sscale[r] = (1.f - copyg[r]) / row_sum[r];
}

// ---------- K3: in-place scale of generation region ----------
__global__ void scale_kernel(float4* __restrict__ out, const float* __restrict__ sscale) {
  const unsigned total = M_ROWS * (N_VOCAB / 4);     // 32.768M float4
  unsigned stride = gridDim.x * blockDim.x;
  for (unsigned i = blockIdx.x * blockDim.x + threadIdx.x; i < total; i += stride) {
    unsigned r = i / (N_VOCAB / 4);
    unsigned c = i % (N_VOCAB / 4);
    float s = sscale[r];
    float4 v = out[(size_t)r * (OUT_PITCH / 4) + c];
    v.x *= s; v.y *= s; v.z *= s; v.w *= s;
    out[(size_t)r * (OUT_PITCH / 4) + c] = v;
  }
}

// ---------- K4: copy branch scatter into extended vocab ----------
__global__ void copyprob_kernel(const float* __restrict__ attn, const int* __restrict__ src_ids,
                                const float* __restrict__ copyg, float* __restrict__ out) {
  unsigned r = blockIdx.x;           // 0..4095
  unsigned tid = threadIdx.x;        // 128 threads
  __shared__ float cp[CV_DIM];
  for (unsigned v = tid; v < CV_DIM; v += 128) cp[v] = 0.f;
  __syncthreads();
  unsigned batch = r >> 7;           // r / T
  float g = copyg[r];
  for (unsigned s = tid; s < S_DIM; s += 128) {
    float a = attn[(size_t)r * S_DIM + s] * g;
    atomicAdd(&cp[src_ids[batch * S_DIM + s]], a);
  }
  __syncthreads();
  for (unsigned v = tid; v < CV_DIM; v += 128)
    out[(size_t)r * OUT_PITCH + N_VOCAB + v] = cp[v];
}

extern "C" void kernel_launch(void* const* d_in, const int* in_sizes, int n_in,
                              void* d_out, int out_size, void* d_ws, size_t ws_size,
                              hipStream_t stream) {
  const float* hidden    = (const float*)d_in[0];   // [4096,512]
  const float* copy_attn = (const float*)d_in[1];   // [4096,400]
  const float* src_map   = (const float*)d_in[2];   // [32,400,600]
  const float* W         = (const float*)d_in[3];   // [32000,512]
  const float* bias      = (const float*)d_in[4];   // [32000]
  const float* w_copy    = (const float*)d_in[5];   // [512]
  const float* b_copy    = (const float*)d_in[6];   // [1]
  float* out = (float*)d_out;

  // workspace layout (all 16B aligned)
  char* ws = (char*)d_ws;
  unsigned short* Wb = (unsigned short*)ws;                               // 32,768,000 B
  unsigned short* Hb = Wb + (size_t)N_VOCAB * K_DIM;                      // +4,194,304
  float* copyg   = (float*)(ws + 36962304);                              // 16 KB
  float* row_sum = (float*)(ws + 36978688);                              // 16 KB
  float* sscale  = (float*)(ws + 36995072);                              // 16 KB
  int*   src_ids = (int*)(ws + 37011456);                                // 51.2 KB

  hipMemsetAsync(row_sum, 0, M_ROWS * sizeof(float), stream);

  // conversions
  cvt_kernel<<<2048, 256, 0, stream>>>((const float4*)W, (ushort4*)Wb,
                                       (unsigned)(N_VOCAB * K_DIM / 4));
  cvt_kernel<<<1024, 256, 0, stream>>>((const float4*)hidden, (ushort4*)Hb,
                                       (unsigned)(M_ROWS * K_DIM / 4));
  // gate + src ids
  copygate_kernel<<<M_ROWS / 4, 256, 0, stream>>>(hidden, w_copy, b_copy, copyg);
  srcids_kernel<<<(32 * S_DIM) / 4, 256, 0, stream>>>(src_map, src_ids);

  // main GEMM + exp epilogue: grid 32 x 250 tiles
  gemm_exp_kernel<<<(M_ROWS / 128) * (N_VOCAB / 128), 256, 0, stream>>>(
      Hb, Wb, bias, out, row_sum);

  finalize_kernel<<<(M_ROWS + 255) / 256, 256, 0, stream>>>(row_sum, copyg, sscale);
  scale_kernel<<<4096, 256, 0, stream>>>((float4*)out, sscale);

  copyprob_kernel<<<M_ROWS, 128, 0, stream>>>(copy_attn, src_ids, copyg, out);
}